// Round 9
// baseline (220.295 us; speedup 1.0000x reference)
//
#include <hip/hip_runtime.h>
#include <hip/hip_bf16.h>
#include <stdint.h>

// Problem constants (B=2, N=M=2048, C=1024, H=16, hd=64)
#define SEQ   2048
#define CH    1024
#define NH    16
#define HD    64

typedef short bf8 __attribute__((ext_vector_type(8)));   // 8 bf16 (4 VGPRs)
typedef short bf4 __attribute__((ext_vector_type(4)));   // 4 bf16 (2 VGPRs)
typedef float f4  __attribute__((ext_vector_type(4)));   // MFMA C/D frag
typedef unsigned short u16;

#define GAS(p) ((const __attribute__((address_space(1))) void*)(p))
#define LAS(p) ((__attribute__((address_space(3))) void*)(p))

__device__ __forceinline__ u16 f2bf(float f) {
  uint32_t u = __float_as_uint(f);
  u += 0x7fffu + ((u >> 16) & 1u);   // RNE
  return (u16)(u >> 16);
}

__device__ __forceinline__ float bf2f(u16 v) {
  return __uint_as_float(((uint32_t)v) << 16);
}

// packed f32x2 -> bf16x2 — PROVEN header path (rounds 4/5/7/8 passed).
// NOTE: hand-written v_cvt_pk_bf16_f32 asm broke correctness in round 6.
__device__ __forceinline__ uint32_t pk2bf(float a, float b) {
  float2 f; f.x = a; f.y = b;
  __hip_bfloat162 h = __float22bfloat162_rn(f);
  union { __hip_bfloat162 h; uint32_t u; } cv; cv.h = h;
  return cv.u;
}

// raw v_exp_f32 via builtin: scores bounded, libm guard not needed (r7 WIN)
__device__ __forceinline__ float fexp2(float x) {
#if __has_builtin(__builtin_amdgcn_exp2f)
  return __builtin_amdgcn_exp2f(x);
#else
  return exp2f(x);
#endif
}

__device__ __forceinline__ f4 MFMA32(bf8 a, bf8 b, f4 c) {
  return __builtin_amdgcn_mfma_f32_16x16x32_bf16(a, b, c, 0, 0, 0);
}

// -------- prep: fp32->bf16 activations + transpose-convert all weights ------
// grid.x: [0,8192) cvt (4 f32/thread) | [8192,12288) 32x32 transpose tiles
__global__ void prep(const float* __restrict__ ref, u16* __restrict__ refb,
                     const float* __restrict__ tgt, u16* __restrict__ tgtb,
                     const float* __restrict__ Wq, u16* __restrict__ Wqt,
                     const float* __restrict__ Wkv, u16* __restrict__ Wkvt,
                     const float* __restrict__ Wp, u16* __restrict__ Wpt) {
  __shared__ float tile[32][33];
  int blk = blockIdx.x;
  int t = threadIdx.x;
  if (blk < 8192) {
    const float* in; u16* out;
    if (blk < 4096) { in = ref; out = refb; } else { in = tgt; out = tgtb; blk -= 4096; }
    int i = (blk * 256 + t) * 4;
    float4 f = *reinterpret_cast<const float4*>(in + i);
    ushort4 o;
    o.x = f2bf(f.x); o.y = f2bf(f.y); o.z = f2bf(f.z); o.w = f2bf(f.w);
    *reinterpret_cast<ushort4*>(out + i) = o;
    return;
  }
  blk -= 8192;                       // 0..4095: x = blk & 127, y = blk >> 7
  int x = blk & 127, by = blk >> 7;
  const float* in; u16* out; int N;
  if (x < 32)       { in = Wq;  out = Wqt;  N = CH;     }
  else if (x < 96)  { in = Wkv; out = Wkvt; N = 2 * CH; x -= 32; }
  else              { in = Wp;  out = Wpt;  N = CH;     x -= 96; }
  const int K = CH;
  int bn = x * 32, bk = by * 32;
  int tx = t & 31, ty = t >> 5;
  #pragma unroll
  for (int i = ty; i < 32; i += 8)
    tile[i][tx] = in[(size_t)(bk + i) * N + bn + tx];
  __syncthreads();
  #pragma unroll
  for (int i = ty; i < 32; i += 8)
    out[(size_t)(bn + i) * K + bk + tx] = f2bf(tile[tx][i]);
}

// ---------------- fused Q-proj + KV-proj GEMM, dbuf, 3 blocks/CU -------------
// blockIdx.x < 16 : KV -> Karr (QK a-frag order) / Varr (PV b-frag order)
// blockIdx.x >= 16: Q  -> q[B,H,M,hd] prescaled by hd^-0.5*log2(e)
__global__ __launch_bounds__(256, 3)
void gemm_qkv(const u16* __restrict__ tgtb, const u16* __restrict__ refb,
              const u16* __restrict__ Wqt, const u16* __restrict__ Wkvt,
              u16* __restrict__ qb, u16* __restrict__ karr, u16* __restrict__ varr)
{
  __shared__ __align__(16) u16 As[2][4096];
  __shared__ __align__(16) u16 Bs[2][4096];
  const int tid = threadIdx.x;
  const int lane = tid & 63, wave = tid >> 6;
  const int l16 = lane & 15, q = lane >> 4;
  const bool isQ = blockIdx.x >= 16;
  const u16* A  = isQ ? tgtb : refb;
  const u16* Bt = isQ ? Wqt : Wkvt;
  const int n0 = (isQ ? (blockIdx.x - 16) : blockIdx.x) * 128;
  const int m0 = blockIdx.y * 128;
  const int wm = (wave >> 1) * 64, wn = (wave & 1) * 64;
  const int Kdim = CH;
  const int c = tid, c2 = tid + 256;
  const int ar = c >> 2, ac = (c & 3) << 3, ar2 = c2 >> 2, ac2 = (c2 & 3) << 3;

  f4 acc[4][4] = {};

  #define STAGE_G(buf, k0)                                                      \
    { __builtin_amdgcn_global_load_lds(                                         \
          GAS(&A[(size_t)(m0 + ar) * Kdim + (k0) + ac]),                        \
          LAS(&As[buf][c << 3]), 16, 0, 0);                                     \
      __builtin_amdgcn_global_load_lds(                                         \
          GAS(&A[(size_t)(m0 + ar2) * Kdim + (k0) + ac2]),                      \
          LAS(&As[buf][c2 << 3]), 16, 0, 0);                                    \
      __builtin_amdgcn_global_load_lds(                                         \
          GAS(&Bt[(size_t)(n0 + ar) * Kdim + (k0) + ac]),                       \
          LAS(&Bs[buf][c << 3]), 16, 0, 0);                                     \
      __builtin_amdgcn_global_load_lds(                                         \
          GAS(&Bt[(size_t)(n0 + ar2) * Kdim + (k0) + ac2]),                     \
          LAS(&Bs[buf][c2 << 3]), 16, 0, 0); }

  STAGE_G(0, 0);
  for (int kk = 0; kk < 32; ++kk) {
    __syncthreads();
    if (kk < 31) STAGE_G((kk + 1) & 1, (kk + 1) * 32);
    const u16* as = As[kk & 1];
    const u16* bs = Bs[kk & 1];
    bf8 a[4], b[4];
    #pragma unroll
    for (int i = 0; i < 4; ++i)
      a[i] = *reinterpret_cast<const bf8*>(&as[(wm + i * 16 + l16) * 32 + q * 8]);
    #pragma unroll
    for (int j = 0; j < 4; ++j)
      b[j] = *reinterpret_cast<const bf8*>(&bs[(wn + j * 16 + l16) * 32 + q * 8]);
    #pragma unroll
    for (int i = 0; i < 4; ++i)
      #pragma unroll
      for (int j = 0; j < 4; ++j)
        acc[i][j] = MFMA32(a[i], b[j], acc[i][j]);
  }
  #undef STAGE_G

  // epilogue — C/D layout: col = lane&15, row = (lane>>4)*4 + reg   [m89/m91]
  #pragma unroll
  for (int i = 0; i < 4; ++i) {
    const int mbase = m0 + wm + i * 16 + q * 4;
    const int b = mbase >> 11, ns0 = mbase & (SEQ - 1);
    #pragma unroll
    for (int j = 0; j < 4; ++j) {
      const int n = n0 + wn + j * 16 + l16;
      if (isQ) {
        int h = n >> 6, d = n & 63;
        #pragma unroll
        for (int r = 0; r < 4; ++r)
          qb[(size_t)((b * NH + h) * SEQ + ns0 + r) * HD + d] =
              f2bf(acc[i][j][r] * 0.1803368801f);
      } else if (n < CH) {  // K -> a-frag order (scalar: r stride = 16B)
        int h = n >> 6, d = n & 63;
        size_t base = (size_t)(b * NH + h) * SEQ * HD;
        int off = (((ns0 >> 4) * 2 + (d >> 5)) * 4 + ((d >> 3) & 3)) * 128
                  + (d & 7);
        #pragma unroll
        for (int r = 0; r < 4; ++r)
          karr[base + off + ((ns0 + r) & 15) * 8] = f2bf(acc[i][j][r]);
      } else {  // V -> paired b-frag order (b128 loads in attn): 8B store
        int c2v = n - CH, h = c2v >> 6, d = c2v & 63;
        size_t base = (size_t)(b * NH + h) * SEQ * HD;
        int off = (((ns0 >> 4) * 2 + (d >> 5)) * 4 + ((ns0 >> 2) & 3)) * 128
                  + (d & 15) * 8 + ((d >> 4) & 1) * 4;
        ushort4 st;
        st.x = f2bf(acc[i][j][0]); st.y = f2bf(acc[i][j][1]);
        st.z = f2bf(acc[i][j][2]); st.w = f2bf(acc[i][j][3]);
        *reinterpret_cast<ushort4*>(&varr[base + off]) = st;
      }
    }
  }
}

// ------- out-proj GEMM: 64x128 tile, grid (8,64)=512 blocks -> 2/CU ---------
__global__ __launch_bounds__(256, 2)
void gemm_proj(const u16* __restrict__ A, const u16* __restrict__ Bt,
               float* __restrict__ fo, const float* __restrict__ bias)
{
  __shared__ __align__(16) u16 As[2][2048];   // 64 x 32
  __shared__ __align__(16) u16 Bs[2][4096];   // 128 x 32
  const int tid = threadIdx.x;
  const int lane = tid & 63, wave = tid >> 6;
  const int l16 = lane & 15, q = lane >> 4;
  const int m0 = blockIdx.y * 64, n0 = blockIdx.x * 128;
  const int wm = (wave >> 1) * 32, wn = (wave & 1) * 64;
  const int Kdim = CH;
  const int c = tid, c2 = tid + 256;
  const int ar = c >> 2, ac = (c & 3) << 3, ar2 = c2 >> 2, ac2 = (c2 & 3) << 3;

  f4 acc[2][4] = {};

  const int aar = c >> 2;            // 0..63
  const int aac = (c & 3) << 3;
  #define STAGE_P(buf, k0)                                                      \
    { __builtin_amdgcn_global_load_lds(                                         \
          GAS(&A[(size_t)(m0 + aar) * Kdim + (k0) + aac]),                      \
          LAS(&As[buf][c << 3]), 16, 0, 0);                                     \
      __builtin_amdgcn_global_load_lds(                                         \
          GAS(&Bt[(size_t)(n0 + ar) * Kdim + (k0) + ac]),                       \
          LAS(&Bs[buf][c << 3]), 16, 0, 0);                                     \
      __builtin_amdgcn_global_load_lds(                                         \
          GAS(&Bt[(size_t)(n0 + ar2) * Kdim + (k0) + ac2]),                     \
          LAS(&Bs[buf][c2 << 3]), 16, 0, 0); }

  STAGE_P(0, 0);
  for (int kk = 0; kk < 32; ++kk) {
    __syncthreads();
    if (kk < 31) STAGE_P((kk + 1) & 1, (kk + 1) * 32);
    const u16* as = As[kk & 1];
    const u16* bs = Bs[kk & 1];
    bf8 a[2], b[4];
    #pragma unroll
    for (int i = 0; i < 2; ++i)
      a[i] = *reinterpret_cast<const bf8*>(&as[(wm + i * 16 + l16) * 32 + q * 8]);
    #pragma unroll
    for (int j = 0; j < 4; ++j)
      b[j] = *reinterpret_cast<const bf8*>(&bs[(wn + j * 16 + l16) * 32 + q * 8]);
    #pragma unroll
    for (int i = 0; i < 2; ++i)
      #pragma unroll
      for (int j = 0; j < 4; ++j)
        acc[i][j] = MFMA32(a[i], b[j], acc[i][j]);
  }
  #undef STAGE_P

  #pragma unroll
  for (int i = 0; i < 2; ++i) {
    const int mbase = m0 + wm + i * 16 + q * 4;
    #pragma unroll
    for (int j = 0; j < 4; ++j) {
      const int n = n0 + wn + j * 16 + l16;
      #pragma unroll
      for (int r = 0; r < 4; ++r)
        fo[(size_t)(mbase + r) * CH + n] = acc[i][j][r] + bias[n];
    }
  }
}

// ------------- flash attention (transposed-S, fixed-max, z-split) -----------
// grid: (M/256, B*H, 2), 512 threads (8 waves); wave owns 32 Q-rows (two
// 16-row groups g=0,1). blockIdx.z picks the sequence half. KVBLK=128.
// Round 9 probe: ALL PV matrix ops moved from the legacy K=16 MFMA to the
// gfx950-native 16x16x32 MFMA with zero-padded A (k-slots 4..7 = 0 in every
// lane -> B high slots are don't-care; identical math, identical op count).
// Tests the hypothesis that v_mfma_f32_16x16x16_bf16 is a slow carry-over
// (accounting: 80 of 112 MFMAs/iter are K=16; MfmaUtil 43% only reconciles
// with ~16cyc/K=16 op). Fixed-max softmax; halves store normalized partial
// x_z and rowsum ds_z; combine = weighted average.
__global__ __launch_bounds__(512, 2)
void attn(const u16* __restrict__ Q, const u16* __restrict__ Karr,
          const u16* __restrict__ Varr, u16* __restrict__ XP,
          float* __restrict__ DS)
{
  __shared__ __align__(16) u16 Ks[2][8192];   // 2 x 16 KB (128 x 64 tile)
  __shared__ __align__(16) u16 Vs[2][8192];   // 2 x 16 KB
  const int tid = threadIdx.x;
  const int lane = tid & 63;
  const int l16 = lane & 15, q = lane >> 4;
  const int bh = blockIdx.y;
  const int z = blockIdx.z;
  const int m0 = blockIdx.x * 256;
  const int wm = (tid >> 6) * 32;             // wave -> 32 Q-rows (8 waves)

  const u16* Qb = Q    + (size_t)bh * SEQ * HD;
  const u16* Kb = Karr + (size_t)bh * SEQ * HD + (size_t)z * 1024 * HD;
  const u16* Vb = Varr + (size_t)bh * SEQ * HD + (size_t)z * 1024 * HD;

  // Q fragments (b-operand layout [n=l16][k=q*8+j]), resident all kernel
  bf8 qf[2][2];
  #pragma unroll
  for (int g = 0; g < 2; ++g)
    #pragma unroll
    for (int s = 0; s < 2; ++s)
      qf[g][s] = *reinterpret_cast<const bf8*>(
          &Qb[(size_t)(m0 + wm + g * 16 + l16) * HD + s * 32 + q * 8]);

  const short ob = (short)0x3F80;            // bf16(1.0)
  const bf8 ones8 = {ob, ob, ob, ob, ob, ob, ob, ob};

  f4 o[2][4] = {};  // O frags per row group: row m=q*4+r, col d=dt*16+l16
  f4 ds[2] = {};    // partial denominators per row group

  // staging: tile = 128 rows x 64 dims = 8192 u16 per array; 512 thr x 16 elems
  #define STAGE_A(buf, t)                                                      \
    { __builtin_amdgcn_global_load_lds(GAS(Kb + (size_t)(t) * 8192 + tid * 8), \
                                       LAS(&Ks[buf][tid * 8]), 16, 0, 0);      \
      __builtin_amdgcn_global_load_lds(GAS(Kb + (size_t)(t) * 8192 + 4096 + tid * 8), \
                                       LAS(&Ks[buf][4096 + tid * 8]), 16, 0, 0); \
      __builtin_amdgcn_global_load_lds(GAS(Vb + (size_t)(t) * 8192 + tid * 8), \
                                       LAS(&Vs[buf][tid * 8]), 16, 0, 0);      \
      __builtin_amdgcn_global_load_lds(GAS(Vb + (size_t)(t) * 8192 + 4096 + tid * 8), \
                                       LAS(&Vs[buf][4096 + tid * 8]), 16, 0, 0); }

  STAGE_A(0, 0);
  for (int t = 0; t < 8; ++t) {
    __syncthreads();
    if (t < 7) STAGE_A((t + 1) & 1, t + 1);
    const u16* ks = Ks[t & 1];
    const u16* vs = Vs[t & 1];

    // S^T tiles + exp + pack into zero-padded A frags (k-slots 4..7 = 0)
    bf8 pz[2][8];
    #pragma unroll
    for (int j = 0; j < 8; ++j) {
      bf8 kf0 = *reinterpret_cast<const bf8*>(&ks[((j * 2 + 0) * 4 + q) * 128 + l16 * 8]);
      bf8 kf1 = *reinterpret_cast<const bf8*>(&ks[((j * 2 + 1) * 4 + q) * 128 + l16 * 8]);
      #pragma unroll
      for (int g = 0; g < 2; ++g) {
        f4 zf = {};
        zf = MFMA32(kf0, qf[g][0], zf);
        zf = MFMA32(kf1, qf[g][1], zf);
        union { bf8 v; uint32_t u[4]; } w;
        w.u[0] = pk2bf(fexp2(zf[0]), fexp2(zf[1]));
        w.u[1] = pk2bf(fexp2(zf[2]), fexp2(zf[3]));
        w.u[2] = 0u;
        w.u[3] = 0u;
        pz[g][j] = w.v;
      }
    }

    // O += P * V ; denominator += P * ones — all via padded K=32 MFMA.
    // A element e (k=q*8+e, e<4 nonzero) needs B element e = V[q*4+e][d]:
    // vv low half IS v0 (even d-block); swap halves for the odd d-block.
    #pragma unroll
    for (int j = 0; j < 8; ++j) {
      ds[0] = MFMA32(pz[0][j], ones8, ds[0]);
      ds[1] = MFMA32(pz[1][j], ones8, ds[1]);
      #pragma unroll
      for (int dh = 0; dh < 2; ++dh) {
        bf8 vv = *reinterpret_cast<const bf8*>(&vs[((j * 2 + dh) * 4 + q) * 128 + l16 * 8]);
        bf8 vswap = __builtin_shufflevector(vv, vv, 4, 5, 6, 7, 0, 1, 2, 3);
        #pragma unroll
        for (int g = 0; g < 2; ++g) {
          o[g][dh * 2 + 0] = MFMA32(pz[g][j], vv,    o[g][dh * 2 + 0]);
          o[g][dh * 2 + 1] = MFMA32(pz[g][j], vswap, o[g][dh * 2 + 1]);
        }
      }
    }
  }
  #undef STAGE_A

  // normalized partial store: XP[z][bh][m][d] bf16, DS[z][bh][m] f32
  #pragma unroll
  for (int g = 0; g < 2; ++g) {
    #pragma unroll
    for (int r = 0; r < 4; ++r) {
      float ir = 1.0f / ds[g][r];
      int m = m0 + wm + g * 16 + q * 4 + r;
      size_t row = (size_t)(z * NH * 2 + bh) * SEQ + m;   // z*32+bh rows
      if (l16 == 0) DS[row] = ds[g][r];
      #pragma unroll
      for (int dt = 0; dt < 4; ++dt) {
        int d = dt * 16 + l16;
        XP[row * HD + d] = f2bf(o[g][dt][r] * ir);
      }
    }
  }
}

// ---- combine halves: X = w0*x0 + w1*x1, w_i = ds_i/(ds0+ds1) ---------------
// grid 4096 x 256: block = 16 rows (of bh*2048+m), 16 threads x 4 d each.
__global__ __launch_bounds__(256)
void combine(const u16* __restrict__ XP, const float* __restrict__ DS,
             u16* __restrict__ xb)
{
  const int t = threadIdx.x;
  const int row = blockIdx.x * 16 + (t >> 4);   // 0..65535 = bh*2048 + m
  const int d0 = (t & 15) * 4;
  const float s0 = DS[row], s1 = DS[65536 + row];
  const float inv = 1.0f / (s0 + s1);
  const float w0 = s0 * inv, w1 = s1 * inv;
  ushort4 a = *reinterpret_cast<const ushort4*>(&XP[(size_t)row * HD + d0]);
  ushort4 b4 = *reinterpret_cast<const ushort4*>(
      &XP[(size_t)(65536 + row) * HD + d0]);
  ushort4 o;
  o.x = f2bf(w0 * bf2f(a.x) + w1 * bf2f(b4.x));
  o.y = f2bf(w0 * bf2f(a.y) + w1 * bf2f(b4.y));
  o.z = f2bf(w0 * bf2f(a.z) + w1 * bf2f(b4.z));
  o.w = f2bf(w0 * bf2f(a.w) + w1 * bf2f(b4.w));
  const int bh = row >> 11, m = row & (SEQ - 1);
  const int b = bh >> 4, h = bh & (NH - 1);
  *reinterpret_cast<ushort4*>(
      &xb[(size_t)(b * SEQ + m) * CH + h * HD + d0]) = o;
}

// ---------------- launch ----------------
extern "C" void kernel_launch(void* const* d_in, const int* in_sizes, int n_in,
                              void* d_out, int out_size, void* d_ws, size_t ws_size,
                              hipStream_t stream) {
  const float* ref   = (const float*)d_in[0];   // [B,N,C]
  const float* tgt   = (const float*)d_in[1];   // [B,M,C]
  const float* Wq    = (const float*)d_in[2];   // [C,C]
  const float* Wkv   = (const float*)d_in[3];   // [C,2C]
  const float* Wproj = (const float*)d_in[4];   // [C,C]
  const float* bproj = (const float*)d_in[5];   // [C]
  float* out = (float*)d_out;                   // [B,M,C] fp32

  // workspace layout (bytes): total 56 MiB
  // [0,16): refb+tgtb (prep->gemm_qkv), then reused as XP (attn->combine)
  // [16,17): Wqt start,              then reused as DS (attn->combine)
  char* ws = (char*)d_ws;
  u16* refb = (u16*)(ws);                 // 8 MiB
  u16* tgtb = (u16*)(ws + (8  << 20));    // 8 MiB
  u16* Wqt  = (u16*)(ws + (16 << 20));    // 2 MiB  [C,C]^T
  u16* Wkvt = (u16*)(ws + (18 << 20));    // 4 MiB  [2C,C]^T
  u16* Wpt  = (u16*)(ws + (22 << 20));    // 2 MiB
  u16* qb   = (u16*)(ws + (24 << 20));    // 8 MiB  [B,H,M,hd] (pre-scaled)
  u16* karr = (u16*)(ws + (32 << 20));    // 8 MiB  a-frag order
  u16* varr = (u16*)(ws + (40 << 20));    // 8 MiB  paired b-frag order
  u16* xb   = (u16*)(ws + (48 << 20));    // 8 MiB  [B*M, C]
  u16*   XP = (u16*)(ws);                 // 16 MiB [2][32][2048][64] bf16
  float* DS = (float*)(ws + (16 << 20));  // 1 MiB  [2][32][2048] f32

  prep<<<12288, 256, 0, stream>>>(ref, refb, tgt, tgtb, Wq, Wqt, Wkv, Wkvt, Wproj, Wpt);

  gemm_qkv<<<dim3(24, 32), 256, 0, stream>>>(tgtb, refb, Wqt, Wkvt, qb, karr, varr);

  attn<<<dim3(8, 32, 2), 512, 0, stream>>>(qb, karr, varr, XP, DS);

  combine<<<4096, 256, 0, stream>>>(XP, DS, xb);

  gemm_proj<<<dim3(8, 64), 256, 0, stream>>>(xb, Wpt, out, bproj);
}

// Round 10
// 209.617 us; speedup vs baseline: 1.0509x; 1.0509x over previous
//
#include <hip/hip_runtime.h>
#include <hip/hip_bf16.h>
#include <stdint.h>

// Problem constants (B=2, N=M=2048, C=1024, H=16, hd=64)
#define SEQ   2048
#define CH    1024
#define NH    16
#define HD    64

typedef short bf8 __attribute__((ext_vector_type(8)));   // 8 bf16 (4 VGPRs)
typedef short bf4 __attribute__((ext_vector_type(4)));   // 4 bf16 (2 VGPRs)
typedef float f4  __attribute__((ext_vector_type(4)));   // MFMA C/D frag
typedef unsigned short u16;

#define GAS(p) ((const __attribute__((address_space(1))) void*)(p))
#define LAS(p) ((__attribute__((address_space(3))) void*)(p))

__device__ __forceinline__ u16 f2bf(float f) {
  uint32_t u = __float_as_uint(f);
  u += 0x7fffu + ((u >> 16) & 1u);   // RNE
  return (u16)(u >> 16);
}

// packed f32x2 -> bf16x2 — PROVEN header path (rounds 4/5/7/8 passed).
// NOTE: hand-written v_cvt_pk_bf16_f32 asm broke correctness in round 6.
__device__ __forceinline__ uint32_t pk2bf(float a, float b) {
  float2 f; f.x = a; f.y = b;
  __hip_bfloat162 h = __float22bfloat162_rn(f);
  union { __hip_bfloat162 h; uint32_t u; } cv; cv.h = h;
  return cv.u;
}

// raw v_exp_f32 via builtin: scores bounded, libm guard not needed (r7 WIN)
__device__ __forceinline__ float fexp2(float x) {
#if __has_builtin(__builtin_amdgcn_exp2f)
  return __builtin_amdgcn_exp2f(x);
#else
  return exp2f(x);
#endif
}

__device__ __forceinline__ f4 MFMA32(bf8 a, bf8 b, f4 c) {
  return __builtin_amdgcn_mfma_f32_16x16x32_bf16(a, b, c, 0, 0, 0);
}

// K=16 MFMA: A-layout [m=l16][k=q*4+reg] == C/D layout of a 16x16 frag.
// r9 probe proved K=16 is NOT slower per-op than K=32 (equal MFMA busy time);
// padded-MFMA32 replacement costs VGPRs/occupancy. Keep MFMA16.
__device__ __forceinline__ f4 MFMA16(bf4 a, bf4 b, f4 c) {
#if __has_builtin(__builtin_amdgcn_mfma_f32_16x16x16_bf16)
  return __builtin_amdgcn_mfma_f32_16x16x16_bf16(a, b, c, 0, 0, 0);
#elif __has_builtin(__builtin_amdgcn_mfma_f32_16x16x16bf16_1k)
  return __builtin_amdgcn_mfma_f32_16x16x16bf16_1k(a, b, c, 0, 0, 0);
#else
  f4 d = c;
  asm volatile("v_mfma_f32_16x16x16_bf16 %0, %1, %2, %0"
               : "+v"(d) : "v"(a), "v"(b));
  return d;
#endif
}

// -------- prep: fp32->bf16 activations + transpose-convert all weights ------
// grid.x: [0,8192) cvt (4 f32/thread) | [8192,12288) 32x32 transpose tiles
__global__ void prep(const float* __restrict__ ref, u16* __restrict__ refb,
                     const float* __restrict__ tgt, u16* __restrict__ tgtb,
                     const float* __restrict__ Wq, u16* __restrict__ Wqt,
                     const float* __restrict__ Wkv, u16* __restrict__ Wkvt,
                     const float* __restrict__ Wp, u16* __restrict__ Wpt) {
  __shared__ float tile[32][33];
  int blk = blockIdx.x;
  int t = threadIdx.x;
  if (blk < 8192) {
    const float* in; u16* out;
    if (blk < 4096) { in = ref; out = refb; } else { in = tgt; out = tgtb; blk -= 4096; }
    int i = (blk * 256 + t) * 4;
    float4 f = *reinterpret_cast<const float4*>(in + i);
    ushort4 o;
    o.x = f2bf(f.x); o.y = f2bf(f.y); o.z = f2bf(f.z); o.w = f2bf(f.w);
    *reinterpret_cast<ushort4*>(out + i) = o;
    return;
  }
  blk -= 8192;                       // 0..4095: x = blk & 127, y = blk >> 7
  int x = blk & 127, by = blk >> 7;
  const float* in; u16* out; int N;
  if (x < 32)       { in = Wq;  out = Wqt;  N = CH;     }
  else if (x < 96)  { in = Wkv; out = Wkvt; N = 2 * CH; x -= 32; }
  else              { in = Wp;  out = Wpt;  N = CH;     x -= 96; }
  const int K = CH;
  int bn = x * 32, bk = by * 32;
  int tx = t & 31, ty = t >> 5;
  #pragma unroll
  for (int i = ty; i < 32; i += 8)
    tile[i][tx] = in[(size_t)(bk + i) * N + bn + tx];
  __syncthreads();
  #pragma unroll
  for (int i = ty; i < 32; i += 8)
    out[(size_t)(bn + i) * K + bk + tx] = f2bf(tile[tx][i]);
}

// ---------------- fused Q-proj + KV-proj GEMM, dbuf, 3 blocks/CU -------------
// blockIdx.x < 16 : KV -> Karr (QK a-frag order) / Varr (PV b-frag order)
// blockIdx.x >= 16: Q  -> q[B,H,M,hd] prescaled by hd^-0.5*log2(e)
__global__ __launch_bounds__(256, 3)
void gemm_qkv(const u16* __restrict__ tgtb, const u16* __restrict__ refb,
              const u16* __restrict__ Wqt, const u16* __restrict__ Wkvt,
              u16* __restrict__ qb, u16* __restrict__ karr, u16* __restrict__ varr)
{
  __shared__ __align__(16) u16 As[2][4096];
  __shared__ __align__(16) u16 Bs[2][4096];
  const int tid = threadIdx.x;
  const int lane = tid & 63, wave = tid >> 6;
  const int l16 = lane & 15, q = lane >> 4;
  const bool isQ = blockIdx.x >= 16;
  const u16* A  = isQ ? tgtb : refb;
  const u16* Bt = isQ ? Wqt : Wkvt;
  const int n0 = (isQ ? (blockIdx.x - 16) : blockIdx.x) * 128;
  const int m0 = blockIdx.y * 128;
  const int wm = (wave >> 1) * 64, wn = (wave & 1) * 64;
  const int Kdim = CH;
  const int c = tid, c2 = tid + 256;
  const int ar = c >> 2, ac = (c & 3) << 3, ar2 = c2 >> 2, ac2 = (c2 & 3) << 3;

  f4 acc[4][4] = {};

  #define STAGE_G(buf, k0)                                                      \
    { __builtin_amdgcn_global_load_lds(                                         \
          GAS(&A[(size_t)(m0 + ar) * Kdim + (k0) + ac]),                        \
          LAS(&As[buf][c << 3]), 16, 0, 0);                                     \
      __builtin_amdgcn_global_load_lds(                                         \
          GAS(&A[(size_t)(m0 + ar2) * Kdim + (k0) + ac2]),                      \
          LAS(&As[buf][c2 << 3]), 16, 0, 0);                                    \
      __builtin_amdgcn_global_load_lds(                                         \
          GAS(&Bt[(size_t)(n0 + ar) * Kdim + (k0) + ac]),                       \
          LAS(&Bs[buf][c << 3]), 16, 0, 0);                                     \
      __builtin_amdgcn_global_load_lds(                                         \
          GAS(&Bt[(size_t)(n0 + ar2) * Kdim + (k0) + ac2]),                     \
          LAS(&Bs[buf][c2 << 3]), 16, 0, 0); }

  STAGE_G(0, 0);
  for (int kk = 0; kk < 32; ++kk) {
    __syncthreads();
    if (kk < 31) STAGE_G((kk + 1) & 1, (kk + 1) * 32);
    const u16* as = As[kk & 1];
    const u16* bs = Bs[kk & 1];
    bf8 a[4], b[4];
    #pragma unroll
    for (int i = 0; i < 4; ++i)
      a[i] = *reinterpret_cast<const bf8*>(&as[(wm + i * 16 + l16) * 32 + q * 8]);
    #pragma unroll
    for (int j = 0; j < 4; ++j)
      b[j] = *reinterpret_cast<const bf8*>(&bs[(wn + j * 16 + l16) * 32 + q * 8]);
    #pragma unroll
    for (int i = 0; i < 4; ++i)
      #pragma unroll
      for (int j = 0; j < 4; ++j)
        acc[i][j] = MFMA32(a[i], b[j], acc[i][j]);
  }
  #undef STAGE_G

  // epilogue — C/D layout: col = lane&15, row = (lane>>4)*4 + reg   [m89/m91]
  #pragma unroll
  for (int i = 0; i < 4; ++i) {
    const int mbase = m0 + wm + i * 16 + q * 4;
    const int b = mbase >> 11, ns0 = mbase & (SEQ - 1);
    #pragma unroll
    for (int j = 0; j < 4; ++j) {
      const int n = n0 + wn + j * 16 + l16;
      if (isQ) {
        int h = n >> 6, d = n & 63;
        #pragma unroll
        for (int r = 0; r < 4; ++r)
          qb[(size_t)((b * NH + h) * SEQ + ns0 + r) * HD + d] =
              f2bf(acc[i][j][r] * 0.1803368801f);
      } else if (n < CH) {  // K -> a-frag order (scalar: r stride = 16B)
        int h = n >> 6, d = n & 63;
        size_t base = (size_t)(b * NH + h) * SEQ * HD;
        int off = (((ns0 >> 4) * 2 + (d >> 5)) * 4 + ((d >> 3) & 3)) * 128
                  + (d & 7);
        #pragma unroll
        for (int r = 0; r < 4; ++r)
          karr[base + off + ((ns0 + r) & 15) * 8] = f2bf(acc[i][j][r]);
      } else {  // V -> paired b-frag order (b128 loads in attn): 8B store
        int c2v = n - CH, h = c2v >> 6, d = c2v & 63;
        size_t base = (size_t)(b * NH + h) * SEQ * HD;
        int off = (((ns0 >> 4) * 2 + (d >> 5)) * 4 + ((ns0 >> 2) & 3)) * 128
                  + (d & 15) * 8 + ((d >> 4) & 1) * 4;
        ushort4 st;
        st.x = f2bf(acc[i][j][0]); st.y = f2bf(acc[i][j][1]);
        st.z = f2bf(acc[i][j][2]); st.w = f2bf(acc[i][j][3]);
        *reinterpret_cast<ushort4*>(&varr[base + off]) = st;
      }
    }
  }
}

// ------- out-proj GEMM: 64x128 tile, grid (8,64)=512 blocks -> 2/CU ---------
__global__ __launch_bounds__(256, 2)
void gemm_proj(const u16* __restrict__ A, const u16* __restrict__ Bt,
               float* __restrict__ fo, const float* __restrict__ bias)
{
  __shared__ __align__(16) u16 As[2][2048];   // 64 x 32
  __shared__ __align__(16) u16 Bs[2][4096];   // 128 x 32
  const int tid = threadIdx.x;
  const int lane = tid & 63, wave = tid >> 6;
  const int l16 = lane & 15, q = lane >> 4;
  const int m0 = blockIdx.y * 64, n0 = blockIdx.x * 128;
  const int wm = (wave >> 1) * 32, wn = (wave & 1) * 64;
  const int Kdim = CH;
  const int c = tid, c2 = tid + 256;
  const int ar = c >> 2, ac = (c & 3) << 3, ar2 = c2 >> 2, ac2 = (c2 & 3) << 3;

  f4 acc[2][4] = {};

  const int aar = c >> 2;            // 0..63
  const int aac = (c & 3) << 3;
  #define STAGE_P(buf, k0)                                                      \
    { __builtin_amdgcn_global_load_lds(                                         \
          GAS(&A[(size_t)(m0 + aar) * Kdim + (k0) + aac]),                      \
          LAS(&As[buf][c << 3]), 16, 0, 0);                                     \
      __builtin_amdgcn_global_load_lds(                                         \
          GAS(&Bt[(size_t)(n0 + ar) * Kdim + (k0) + ac]),                       \
          LAS(&Bs[buf][c << 3]), 16, 0, 0);                                     \
      __builtin_amdgcn_global_load_lds(                                         \
          GAS(&Bt[(size_t)(n0 + ar2) * Kdim + (k0) + ac2]),                     \
          LAS(&Bs[buf][c2 << 3]), 16, 0, 0); }

  STAGE_P(0, 0);
  for (int kk = 0; kk < 32; ++kk) {
    __syncthreads();
    if (kk < 31) STAGE_P((kk + 1) & 1, (kk + 1) * 32);
    const u16* as = As[kk & 1];
    const u16* bs = Bs[kk & 1];
    bf8 a[2], b[4];
    #pragma unroll
    for (int i = 0; i < 2; ++i)
      a[i] = *reinterpret_cast<const bf8*>(&as[(wm + i * 16 + l16) * 32 + q * 8]);
    #pragma unroll
    for (int j = 0; j < 4; ++j)
      b[j] = *reinterpret_cast<const bf8*>(&bs[(wn + j * 16 + l16) * 32 + q * 8]);
    #pragma unroll
    for (int i = 0; i < 2; ++i)
      #pragma unroll
      for (int j = 0; j < 4; ++j)
        acc[i][j] = MFMA32(a[i], b[j], acc[i][j]);
  }
  #undef STAGE_P

  #pragma unroll
  for (int i = 0; i < 2; ++i) {
    const int mbase = m0 + wm + i * 16 + q * 4;
    #pragma unroll
    for (int j = 0; j < 4; ++j) {
      const int n = n0 + wn + j * 16 + l16;
      #pragma unroll
      for (int r = 0; r < 4; ++r)
        fo[(size_t)(mbase + r) * CH + n] = acc[i][j][r] + bias[n];
    }
  }
}

// ------------- flash attention (transposed-S, fixed-max, NO split) ----------
// grid: (M/128, B*H), 256 threads (4 waves); wave owns 32 Q-rows (two
// 16-row groups g=0,1). Each block walks the FULL sequence (KVBLK=64,
// 32 t-iters, LDS 32 KB). Round 10: z-split removed — r4/r5 proved waves/CU
// between 16 and 32 doesn't move duration, so halving to 8 should be ~free
// and deletes the combine kernel + ~25 MB XP/DS round-trip. Inner loop is
// byte-identical to round 7's passing kernel; epilogue = baseline normalize
// + direct xb store (proven in r0).
__global__ __launch_bounds__(256, 4)
void attn(const u16* __restrict__ Q, const u16* __restrict__ Karr,
          const u16* __restrict__ Varr, u16* __restrict__ X)
{
  __shared__ __align__(16) u16 Ks[2][4096];   // 2 x 8 KB (64 x 64 tile)
  __shared__ __align__(16) u16 Vs[2][4096];   // 2 x 8 KB
  const int tid = threadIdx.x;
  const int lane = tid & 63;
  const int l16 = lane & 15, q = lane >> 4;
  const int bh = blockIdx.y;
  const int m0 = blockIdx.x * 128;
  const int wm = (tid >> 6) * 32;             // wave -> 32 Q-rows

  const u16* Qb = Q    + (size_t)bh * SEQ * HD;
  const u16* Kb = Karr + (size_t)bh * SEQ * HD;
  const u16* Vb = Varr + (size_t)bh * SEQ * HD;

  // Q fragments (b-operand layout [n=l16][k=q*8+j]), resident all kernel
  bf8 qf[2][2];
  #pragma unroll
  for (int g = 0; g < 2; ++g)
    #pragma unroll
    for (int s = 0; s < 2; ++s)
      qf[g][s] = *reinterpret_cast<const bf8*>(
          &Qb[(size_t)(m0 + wm + g * 16 + l16) * HD + s * 32 + q * 8]);

  const short one_bf = 0x3F80;               // bf16(1.0)
  const bf4 ones = {one_bf, one_bf, one_bf, one_bf};

  f4 o[2][4] = {};  // O frags per row group: row m=q*4+r, col d=dt*16+l16
  f4 ds[2] = {};    // denominators per row group

  // staging: tile = 64 rows x 64 dims = 4096 u16 per array; 256 thr x 16 elems
  #define STAGE_A(buf, t)                                                      \
    { __builtin_amdgcn_global_load_lds(GAS(Kb + (size_t)(t) * 4096 + tid * 8), \
                                       LAS(&Ks[buf][tid * 8]), 16, 0, 0);      \
      __builtin_amdgcn_global_load_lds(GAS(Kb + (size_t)(t) * 4096 + 2048 + tid * 8), \
                                       LAS(&Ks[buf][2048 + tid * 8]), 16, 0, 0); \
      __builtin_amdgcn_global_load_lds(GAS(Vb + (size_t)(t) * 4096 + tid * 8), \
                                       LAS(&Vs[buf][tid * 8]), 16, 0, 0);      \
      __builtin_amdgcn_global_load_lds(GAS(Vb + (size_t)(t) * 4096 + 2048 + tid * 8), \
                                       LAS(&Vs[buf][2048 + tid * 8]), 16, 0, 0); }

  STAGE_A(0, 0);
  for (int t = 0; t < 32; ++t) {
    __syncthreads();
    if (t < 31) STAGE_A((t + 1) & 1, t + 1);
    const u16* ks = Ks[t & 1];
    const u16* vs = Vs[t & 1];

    // S^T tiles + exp + pack; each K-fragment pair feeds BOTH row groups
    bf4 pa[2][4];
    #pragma unroll
    for (int j = 0; j < 4; ++j) {
      bf8 kf0 = *reinterpret_cast<const bf8*>(&ks[((j * 2 + 0) * 4 + q) * 128 + l16 * 8]);
      bf8 kf1 = *reinterpret_cast<const bf8*>(&ks[((j * 2 + 1) * 4 + q) * 128 + l16 * 8]);
      #pragma unroll
      for (int g = 0; g < 2; ++g) {
        f4 zf = {};
        zf = MFMA32(kf0, qf[g][0], zf);
        zf = MFMA32(kf1, qf[g][1], zf);
        union { bf4 v; uint32_t u[2]; } w;
        w.u[0] = pk2bf(fexp2(zf[0]), fexp2(zf[1]));
        w.u[1] = pk2bf(fexp2(zf[2]), fexp2(zf[3]));
        pa[g][j] = w.v;
      }
    }

    // O += P * V ; denominator += P * ones; each V-fragment feeds both groups
    #pragma unroll
    for (int j = 0; j < 4; ++j) {
      ds[0] = MFMA16(pa[0][j], ones, ds[0]);
      ds[1] = MFMA16(pa[1][j], ones, ds[1]);
      #pragma unroll
      for (int dh = 0; dh < 2; ++dh) {
        bf8 vv = *reinterpret_cast<const bf8*>(&vs[((j * 2 + dh) * 4 + q) * 128 + l16 * 8]);
        bf4 v0 = __builtin_shufflevector(vv, vv, 0, 1, 2, 3);
        bf4 v1 = __builtin_shufflevector(vv, vv, 4, 5, 6, 7);
        #pragma unroll
        for (int g = 0; g < 2; ++g) {
          o[g][dh * 2 + 0] = MFMA16(pa[g][j], v0, o[g][dh * 2 + 0]);
          o[g][dh * 2 + 1] = MFMA16(pa[g][j], v1, o[g][dh * 2 + 1]);
        }
      }
    }
  }
  #undef STAGE_A

  // normalize + write x[b, m, h*64+d] (bf16) directly — no combine pass
  const int b = bh >> 4, h = bh & (NH - 1);
  #pragma unroll
  for (int g = 0; g < 2; ++g) {
    #pragma unroll
    for (int r = 0; r < 4; ++r) {
      float ir = 1.0f / ds[g][r];
      int m = m0 + wm + g * 16 + q * 4 + r;
      #pragma unroll
      for (int dt = 0; dt < 4; ++dt) {
        int d = dt * 16 + l16;
        X[(size_t)(b * SEQ + m) * CH + h * HD + d] = f2bf(o[g][dt][r] * ir);
      }
    }
  }
}

// ---------------- launch ----------------
extern "C" void kernel_launch(void* const* d_in, const int* in_sizes, int n_in,
                              void* d_out, int out_size, void* d_ws, size_t ws_size,
                              hipStream_t stream) {
  const float* ref   = (const float*)d_in[0];   // [B,N,C]
  const float* tgt   = (const float*)d_in[1];   // [B,M,C]
  const float* Wq    = (const float*)d_in[2];   // [C,C]
  const float* Wkv   = (const float*)d_in[3];   // [C,2C]
  const float* Wproj = (const float*)d_in[4];   // [C,C]
  const float* bproj = (const float*)d_in[5];   // [C]
  float* out = (float*)d_out;                   // [B,M,C] fp32

  // workspace layout (bytes): total 56 MiB
  char* ws = (char*)d_ws;
  u16* refb = (u16*)(ws);                 // 8 MiB
  u16* tgtb = (u16*)(ws + (8  << 20));    // 8 MiB
  u16* Wqt  = (u16*)(ws + (16 << 20));    // 2 MiB  [C,C]^T
  u16* Wkvt = (u16*)(ws + (18 << 20));    // 4 MiB  [2C,C]^T
  u16* Wpt  = (u16*)(ws + (22 << 20));    // 2 MiB
  u16* qb   = (u16*)(ws + (24 << 20));    // 8 MiB  [B,H,M,hd] (pre-scaled)
  u16* karr = (u16*)(ws + (32 << 20));    // 8 MiB  a-frag order
  u16* varr = (u16*)(ws + (40 << 20));    // 8 MiB  paired b-frag order
  u16* xb   = (u16*)(ws + (48 << 20));    // 8 MiB  [B*M, C]

  prep<<<12288, 256, 0, stream>>>(ref, refb, tgt, tgtb, Wq, Wqt, Wkv, Wkvt, Wproj, Wpt);

  gemm_qkv<<<dim3(24, 32), 256, 0, stream>>>(tgtb, refb, Wqt, Wkvt, qb, karr, varr);

  attn<<<dim3(16, 32), 256, 0, stream>>>(qb, karr, varr, xb);

  gemm_proj<<<dim3(8, 64), 256, 0, stream>>>(xb, Wpt, out, bproj);
}

// Round 11
// 207.414 us; speedup vs baseline: 1.0621x; 1.0106x over previous
//
#include <hip/hip_runtime.h>
#include <hip/hip_bf16.h>
#include <stdint.h>

// Problem constants (B=2, N=M=2048, C=1024, H=16, hd=64)
#define SEQ   2048
#define CH    1024
#define NH    16
#define HD    64

typedef short bf8 __attribute__((ext_vector_type(8)));   // 8 bf16 (4 VGPRs)
typedef short bf4 __attribute__((ext_vector_type(4)));   // 4 bf16 (2 VGPRs)
typedef float f4  __attribute__((ext_vector_type(4)));   // MFMA C/D frag
typedef unsigned short u16;

#define GAS(p) ((const __attribute__((address_space(1))) void*)(p))
#define LAS(p) ((__attribute__((address_space(3))) void*)(p))

__device__ __forceinline__ u16 f2bf(float f) {
  uint32_t u = __float_as_uint(f);
  u += 0x7fffu + ((u >> 16) & 1u);   // RNE
  return (u16)(u >> 16);
}

// packed f32x2 -> bf16x2 — PROVEN header path (rounds 4/5/7/8/10 passed).
// NOTE: hand-written v_cvt_pk_bf16_f32 asm broke correctness in round 6.
__device__ __forceinline__ uint32_t pk2bf(float a, float b) {
  float2 f; f.x = a; f.y = b;
  __hip_bfloat162 h = __float22bfloat162_rn(f);
  union { __hip_bfloat162 h; uint32_t u; } cv; cv.h = h;
  return cv.u;
}

// raw v_exp_f32 via builtin: scores bounded, libm guard not needed (r7 WIN)
__device__ __forceinline__ float fexp2(float x) {
#if __has_builtin(__builtin_amdgcn_exp2f)
  return __builtin_amdgcn_exp2f(x);
#else
  return exp2f(x);
#endif
}

__device__ __forceinline__ f4 MFMA32(bf8 a, bf8 b, f4 c) {
  return __builtin_amdgcn_mfma_f32_16x16x32_bf16(a, b, c, 0, 0, 0);
}

// K=16 MFMA: A-layout [m=l16][k=q*4+reg] == C/D layout of a 16x16 frag.
// r9 probe proved K=16 is NOT slower per-op than K=32; keep MFMA16.
__device__ __forceinline__ f4 MFMA16(bf4 a, bf4 b, f4 c) {
#if __has_builtin(__builtin_amdgcn_mfma_f32_16x16x16_bf16)
  return __builtin_amdgcn_mfma_f32_16x16x16_bf16(a, b, c, 0, 0, 0);
#elif __has_builtin(__builtin_amdgcn_mfma_f32_16x16x16bf16_1k)
  return __builtin_amdgcn_mfma_f32_16x16x16bf16_1k(a, b, c, 0, 0, 0);
#else
  f4 d = c;
  asm volatile("v_mfma_f32_16x16x16_bf16 %0, %1, %2, %0"
               : "+v"(d) : "v"(a), "v"(b));
  return d;
#endif
}

// -------- prep: fp32->bf16 activations + transpose-convert all weights ------
// grid.x: [0,8192) cvt (4 f32/thread) | [8192,12288) 32x32 transpose tiles
__global__ void prep(const float* __restrict__ ref, u16* __restrict__ refb,
                     const float* __restrict__ tgt, u16* __restrict__ tgtb,
                     const float* __restrict__ Wq, u16* __restrict__ Wqt,
                     const float* __restrict__ Wkv, u16* __restrict__ Wkvt,
                     const float* __restrict__ Wp, u16* __restrict__ Wpt) {
  __shared__ float tile[32][33];
  int blk = blockIdx.x;
  int t = threadIdx.x;
  if (blk < 8192) {
    const float* in; u16* out;
    if (blk < 4096) { in = ref; out = refb; } else { in = tgt; out = tgtb; blk -= 4096; }
    int i = (blk * 256 + t) * 4;
    float4 f = *reinterpret_cast<const float4*>(in + i);
    ushort4 o;
    o.x = f2bf(f.x); o.y = f2bf(f.y); o.z = f2bf(f.z); o.w = f2bf(f.w);
    *reinterpret_cast<ushort4*>(out + i) = o;
    return;
  }
  blk -= 8192;                       // 0..4095: x = blk & 127, y = blk >> 7
  int x = blk & 127, by = blk >> 7;
  const float* in; u16* out; int N;
  if (x < 32)       { in = Wq;  out = Wqt;  N = CH;     }
  else if (x < 96)  { in = Wkv; out = Wkvt; N = 2 * CH; x -= 32; }
  else              { in = Wp;  out = Wpt;  N = CH;     x -= 96; }
  const int K = CH;
  int bn = x * 32, bk = by * 32;
  int tx = t & 31, ty = t >> 5;
  #pragma unroll
  for (int i = ty; i < 32; i += 8)
    tile[i][tx] = in[(size_t)(bk + i) * N + bn + tx];
  __syncthreads();
  #pragma unroll
  for (int i = ty; i < 32; i += 8)
    out[(size_t)(bn + i) * K + bk + tx] = f2bf(tile[tx][i]);
}

// ---------------- fused Q-proj + KV-proj GEMM, dbuf, 3 blocks/CU -------------
// blockIdx.x < 16 : KV -> Karr (QK a-frag order) / Varr (PV b-frag order)
// blockIdx.x >= 16: Q  -> q[B,H,M,hd] prescaled by hd^-0.5*log2(e)
__global__ __launch_bounds__(256, 3)
void gemm_qkv(const u16* __restrict__ tgtb, const u16* __restrict__ refb,
              const u16* __restrict__ Wqt, const u16* __restrict__ Wkvt,
              u16* __restrict__ qb, u16* __restrict__ karr, u16* __restrict__ varr)
{
  __shared__ __align__(16) u16 As[2][4096];
  __shared__ __align__(16) u16 Bs[2][4096];
  const int tid = threadIdx.x;
  const int lane = tid & 63, wave = tid >> 6;
  const int l16 = lane & 15, q = lane >> 4;
  const bool isQ = blockIdx.x >= 16;
  const u16* A  = isQ ? tgtb : refb;
  const u16* Bt = isQ ? Wqt : Wkvt;
  const int n0 = (isQ ? (blockIdx.x - 16) : blockIdx.x) * 128;
  const int m0 = blockIdx.y * 128;
  const int wm = (wave >> 1) * 64, wn = (wave & 1) * 64;
  const int Kdim = CH;
  const int c = tid, c2 = tid + 256;
  const int ar = c >> 2, ac = (c & 3) << 3, ar2 = c2 >> 2, ac2 = (c2 & 3) << 3;

  f4 acc[4][4] = {};

  #define STAGE_G(buf, k0)                                                      \
    { __builtin_amdgcn_global_load_lds(                                         \
          GAS(&A[(size_t)(m0 + ar) * Kdim + (k0) + ac]),                        \
          LAS(&As[buf][c << 3]), 16, 0, 0);                                     \
      __builtin_amdgcn_global_load_lds(                                         \
          GAS(&A[(size_t)(m0 + ar2) * Kdim + (k0) + ac2]),                      \
          LAS(&As[buf][c2 << 3]), 16, 0, 0);                                    \
      __builtin_amdgcn_global_load_lds(                                         \
          GAS(&Bt[(size_t)(n0 + ar) * Kdim + (k0) + ac]),                       \
          LAS(&Bs[buf][c << 3]), 16, 0, 0);                                     \
      __builtin_amdgcn_global_load_lds(                                         \
          GAS(&Bt[(size_t)(n0 + ar2) * Kdim + (k0) + ac2]),                     \
          LAS(&Bs[buf][c2 << 3]), 16, 0, 0); }

  STAGE_G(0, 0);
  for (int kk = 0; kk < 32; ++kk) {
    __syncthreads();
    if (kk < 31) STAGE_G((kk + 1) & 1, (kk + 1) * 32);
    const u16* as = As[kk & 1];
    const u16* bs = Bs[kk & 1];
    bf8 a[4], b[4];
    #pragma unroll
    for (int i = 0; i < 4; ++i)
      a[i] = *reinterpret_cast<const bf8*>(&as[(wm + i * 16 + l16) * 32 + q * 8]);
    #pragma unroll
    for (int j = 0; j < 4; ++j)
      b[j] = *reinterpret_cast<const bf8*>(&bs[(wn + j * 16 + l16) * 32 + q * 8]);
    #pragma unroll
    for (int i = 0; i < 4; ++i)
      #pragma unroll
      for (int j = 0; j < 4; ++j)
        acc[i][j] = MFMA32(a[i], b[j], acc[i][j]);
  }
  #undef STAGE_G

  // epilogue — C/D layout: col = lane&15, row = (lane>>4)*4 + reg   [m89/m91]
  #pragma unroll
  for (int i = 0; i < 4; ++i) {
    const int mbase = m0 + wm + i * 16 + q * 4;
    const int b = mbase >> 11, ns0 = mbase & (SEQ - 1);
    #pragma unroll
    for (int j = 0; j < 4; ++j) {
      const int n = n0 + wn + j * 16 + l16;
      if (isQ) {
        int h = n >> 6, d = n & 63;
        #pragma unroll
        for (int r = 0; r < 4; ++r)
          qb[(size_t)((b * NH + h) * SEQ + ns0 + r) * HD + d] =
              f2bf(acc[i][j][r] * 0.1803368801f);
      } else if (n < CH) {  // K -> a-frag order (scalar: r stride = 16B)
        int h = n >> 6, d = n & 63;
        size_t base = (size_t)(b * NH + h) * SEQ * HD;
        int off = (((ns0 >> 4) * 2 + (d >> 5)) * 4 + ((d >> 3) & 3)) * 128
                  + (d & 7);
        #pragma unroll
        for (int r = 0; r < 4; ++r)
          karr[base + off + ((ns0 + r) & 15) * 8] = f2bf(acc[i][j][r]);
      } else {  // V -> paired b-frag order (b128 loads in attn): 8B store
        int c2v = n - CH, h = c2v >> 6, d = c2v & 63;
        size_t base = (size_t)(b * NH + h) * SEQ * HD;
        int off = (((ns0 >> 4) * 2 + (d >> 5)) * 4 + ((ns0 >> 2) & 3)) * 128
                  + (d & 15) * 8 + ((d >> 4) & 1) * 4;
        ushort4 st;
        st.x = f2bf(acc[i][j][0]); st.y = f2bf(acc[i][j][1]);
        st.z = f2bf(acc[i][j][2]); st.w = f2bf(acc[i][j][3]);
        *reinterpret_cast<ushort4*>(&varr[base + off]) = st;
      }
    }
  }
}

// ------- out-proj GEMM: 64x128 tile, grid (8,64)=512 blocks -> 2/CU ---------
__global__ __launch_bounds__(256, 2)
void gemm_proj(const u16* __restrict__ A, const u16* __restrict__ Bt,
               float* __restrict__ fo, const float* __restrict__ bias)
{
  __shared__ __align__(16) u16 As[2][2048];   // 64 x 32
  __shared__ __align__(16) u16 Bs[2][4096];   // 128 x 32
  const int tid = threadIdx.x;
  const int lane = tid & 63, wave = tid >> 6;
  const int l16 = lane & 15, q = lane >> 4;
  const int m0 = blockIdx.y * 64, n0 = blockIdx.x * 128;
  const int wm = (wave >> 1) * 32, wn = (wave & 1) * 64;
  const int Kdim = CH;
  const int c = tid, c2 = tid + 256;
  const int ar = c >> 2, ac = (c & 3) << 3, ar2 = c2 >> 2, ac2 = (c2 & 3) << 3;

  f4 acc[2][4] = {};

  const int aar = c >> 2;            // 0..63
  const int aac = (c & 3) << 3;
  #define STAGE_P(buf, k0)                                                      \
    { __builtin_amdgcn_global_load_lds(                                         \
          GAS(&A[(size_t)(m0 + aar) * Kdim + (k0) + aac]),                      \
          LAS(&As[buf][c << 3]), 16, 0, 0);                                     \
      __builtin_amdgcn_global_load_lds(                                         \
          GAS(&Bt[(size_t)(n0 + ar) * Kdim + (k0) + ac]),                       \
          LAS(&Bs[buf][c << 3]), 16, 0, 0);                                     \
      __builtin_amdgcn_global_load_lds(                                         \
          GAS(&Bt[(size_t)(n0 + ar2) * Kdim + (k0) + ac2]),                     \
          LAS(&Bs[buf][c2 << 3]), 16, 0, 0); }

  STAGE_P(0, 0);
  for (int kk = 0; kk < 32; ++kk) {
    __syncthreads();
    if (kk < 31) STAGE_P((kk + 1) & 1, (kk + 1) * 32);
    const u16* as = As[kk & 1];
    const u16* bs = Bs[kk & 1];
    bf8 a[2], b[4];
    #pragma unroll
    for (int i = 0; i < 2; ++i)
      a[i] = *reinterpret_cast<const bf8*>(&as[(wm + i * 16 + l16) * 32 + q * 8]);
    #pragma unroll
    for (int j = 0; j < 4; ++j)
      b[j] = *reinterpret_cast<const bf8*>(&bs[(wn + j * 16 + l16) * 32 + q * 8]);
    #pragma unroll
    for (int i = 0; i < 2; ++i)
      #pragma unroll
      for (int j = 0; j < 4; ++j)
        acc[i][j] = MFMA32(a[i], b[j], acc[i][j]);
  }
  #undef STAGE_P

  #pragma unroll
  for (int i = 0; i < 2; ++i) {
    const int mbase = m0 + wm + i * 16 + q * 4;
    #pragma unroll
    for (int j = 0; j < 4; ++j) {
      const int n = n0 + wn + j * 16 + l16;
      #pragma unroll
      for (int r = 0; r < 4; ++r)
        fo[(size_t)(mbase + r) * CH + n] = acc[i][j][r] + bias[n];
    }
  }
}

// ------------- flash attention (transposed-S, fixed-max, NO split) ----------
// grid: (M/64, B*H), 256 threads (4 waves); wave owns 16 Q-rows (r4's proven
// inner math, no g-loop). Full sequence per block (KVBLK=64, 32 t-iters,
// LDS 32 KB). 1024 blocks -> 4 blocks/CU -> 16 waves/CU: restores r7's
// occupancy (the r10 post-mortem's knee: 8->16 waves/CU was worth ~13%)
// WITHOUT the z-split/combine machinery (r10 proved it unnecessary).
__global__ __launch_bounds__(256, 4)
void attn(const u16* __restrict__ Q, const u16* __restrict__ Karr,
          const u16* __restrict__ Varr, u16* __restrict__ X)
{
  __shared__ __align__(16) u16 Ks[2][4096];   // 2 x 8 KB (64 x 64 tile)
  __shared__ __align__(16) u16 Vs[2][4096];   // 2 x 8 KB
  const int tid = threadIdx.x;
  const int lane = tid & 63;
  const int l16 = lane & 15, q = lane >> 4;
  const int bh = blockIdx.y;
  const int m0 = blockIdx.x * 64;
  const int wm = (tid >> 6) * 16;             // wave -> 16 Q-rows

  const u16* Qb = Q    + (size_t)bh * SEQ * HD;
  const u16* Kb = Karr + (size_t)bh * SEQ * HD;
  const u16* Vb = Varr + (size_t)bh * SEQ * HD;

  // Q fragments (b-operand layout [n=l16][k=q*8+j]), resident all kernel
  bf8 qf[2];
  #pragma unroll
  for (int s = 0; s < 2; ++s)
    qf[s] = *reinterpret_cast<const bf8*>(
        &Qb[(size_t)(m0 + wm + l16) * HD + s * 32 + q * 8]);

  const short one_bf = 0x3F80;               // bf16(1.0)
  const bf4 ones = {one_bf, one_bf, one_bf, one_bf};

  f4 o[4] = {};     // O frag: row m=q*4+r, col d=dt*16+l16
  f4 ds = {};       // denominator frag: ds[r] = rowsum for m=q*4+r

  // staging: tile = 64 rows x 64 dims = 4096 u16 per array; 256 thr x 16 elems
  #define STAGE_A(buf, t)                                                      \
    { __builtin_amdgcn_global_load_lds(GAS(Kb + (size_t)(t) * 4096 + tid * 8), \
                                       LAS(&Ks[buf][tid * 8]), 16, 0, 0);      \
      __builtin_amdgcn_global_load_lds(GAS(Kb + (size_t)(t) * 4096 + 2048 + tid * 8), \
                                       LAS(&Ks[buf][2048 + tid * 8]), 16, 0, 0); \
      __builtin_amdgcn_global_load_lds(GAS(Vb + (size_t)(t) * 4096 + tid * 8), \
                                       LAS(&Vs[buf][tid * 8]), 16, 0, 0);      \
      __builtin_amdgcn_global_load_lds(GAS(Vb + (size_t)(t) * 4096 + 2048 + tid * 8), \
                                       LAS(&Vs[buf][2048 + tid * 8]), 16, 0, 0); }

  STAGE_A(0, 0);
  for (int t = 0; t < 32; ++t) {
    __syncthreads();
    if (t < 31) STAGE_A((t + 1) & 1, t + 1);
    const u16* ks = Ks[t & 1];
    const u16* vs = Vs[t & 1];

    // S^T tiles + exp + pack, all in registers (4 x 16 k-rows per step)
    bf4 pa[4];
    #pragma unroll
    for (int j = 0; j < 4; ++j) {
      bf8 kf0 = *reinterpret_cast<const bf8*>(&ks[((j * 2 + 0) * 4 + q) * 128 + l16 * 8]);
      bf8 kf1 = *reinterpret_cast<const bf8*>(&ks[((j * 2 + 1) * 4 + q) * 128 + l16 * 8]);
      f4 zf = {};
      zf = MFMA32(kf0, qf[0], zf);
      zf = MFMA32(kf1, qf[1], zf);
      union { bf4 v; uint32_t u[2]; } w;
      w.u[0] = pk2bf(fexp2(zf[0]), fexp2(zf[1]));
      w.u[1] = pk2bf(fexp2(zf[2]), fexp2(zf[3]));
      pa[j] = w.v;
    }

    // O += P * V ; denominator += P * ones; V frags as b128 pairs
    #pragma unroll
    for (int j = 0; j < 4; ++j) {
      ds = MFMA16(pa[j], ones, ds);
      #pragma unroll
      for (int dh = 0; dh < 2; ++dh) {
        bf8 vv = *reinterpret_cast<const bf8*>(&vs[((j * 2 + dh) * 4 + q) * 128 + l16 * 8]);
        bf4 v0 = __builtin_shufflevector(vv, vv, 0, 1, 2, 3);
        bf4 v1 = __builtin_shufflevector(vv, vv, 4, 5, 6, 7);
        o[dh * 2 + 0] = MFMA16(pa[j], v0, o[dh * 2 + 0]);
        o[dh * 2 + 1] = MFMA16(pa[j], v1, o[dh * 2 + 1]);
      }
    }
  }
  #undef STAGE_A

  // normalize + write x[b, m, h*64+d] (bf16) directly — no combine pass
  const int b = bh >> 4, h = bh & (NH - 1);
  #pragma unroll
  for (int r = 0; r < 4; ++r) {
    float ir = 1.0f / ds[r];
    int m = m0 + wm + q * 4 + r;
    #pragma unroll
    for (int dt = 0; dt < 4; ++dt) {
      int d = dt * 16 + l16;
      X[(size_t)(b * SEQ + m) * CH + h * HD + d] = f2bf(o[dt][r] * ir);
    }
  }
}

// ---------------- launch ----------------
extern "C" void kernel_launch(void* const* d_in, const int* in_sizes, int n_in,
                              void* d_out, int out_size, void* d_ws, size_t ws_size,
                              hipStream_t stream) {
  const float* ref   = (const float*)d_in[0];   // [B,N,C]
  const float* tgt   = (const float*)d_in[1];   // [B,M,C]
  const float* Wq    = (const float*)d_in[2];   // [C,C]
  const float* Wkv   = (const float*)d_in[3];   // [C,2C]
  const float* Wproj = (const float*)d_in[4];   // [C,C]
  const float* bproj = (const float*)d_in[5];   // [C]
  float* out = (float*)d_out;                   // [B,M,C] fp32

  // workspace layout (bytes): total 56 MiB
  char* ws = (char*)d_ws;
  u16* refb = (u16*)(ws);                 // 8 MiB
  u16* tgtb = (u16*)(ws + (8  << 20));    // 8 MiB
  u16* Wqt  = (u16*)(ws + (16 << 20));    // 2 MiB  [C,C]^T
  u16* Wkvt = (u16*)(ws + (18 << 20));    // 4 MiB  [2C,C]^T
  u16* Wpt  = (u16*)(ws + (22 << 20));    // 2 MiB
  u16* qb   = (u16*)(ws + (24 << 20));    // 8 MiB  [B,H,M,hd] (pre-scaled)
  u16* karr = (u16*)(ws + (32 << 20));    // 8 MiB  a-frag order
  u16* varr = (u16*)(ws + (40 << 20));    // 8 MiB  paired b-frag order
  u16* xb   = (u16*)(ws + (48 << 20));    // 8 MiB  [B*M, C]

  prep<<<12288, 256, 0, stream>>>(ref, refb, tgt, tgtb, Wq, Wqt, Wkv, Wkvt, Wproj, Wpt);

  gemm_qkv<<<dim3(24, 32), 256, 0, stream>>>(tgtb, refb, Wqt, Wkvt, qb, karr, varr);

  attn<<<dim3(32, 32), 256, 0, stream>>>(qb, karr, varr, xb);

  gemm_proj<<<dim3(8, 64), 256, 0, stream>>>(xb, Wpt, out, bproj);
}